// Round 1
// baseline (4797.527 us; speedup 1.0000x reference)
//
#include <hip/hip_runtime.h>

#define HD  64      // hidden dim
#define BPW 8       // batches per workgroup
#define NT  768     // threads per block = 12 waves

__device__ __forceinline__ float fast_sig(float x) {
    return __builtin_amdgcn_rcpf(1.0f + __expf(-x));
}
__device__ __forceinline__ float fast_tanh(float x) {
    float e = __expf(2.0f * x);
    return (e - 1.0f) * __builtin_amdgcn_rcpf(e + 1.0f);
}

extern "C" __global__ void __launch_bounds__(NT, 3)
lstm2_kernel(const float* __restrict__ x,
             const float* __restrict__ Wih0, const float* __restrict__ Whh0,
             const float* __restrict__ bih0, const float* __restrict__ bhh0,
             const float* __restrict__ Wih1, const float* __restrict__ Whh1,
             const float* __restrict__ bih1, const float* __restrict__ bhh1,
             const float* __restrict__ Wc1,  const float* __restrict__ bc1,
             const float* __restrict__ Wc2,  const float* __restrict__ bc2,
             float* __restrict__ out, int B, int T)
{
    __shared__ float h0s[BPW][HD];        // layer0 hidden h0[tau-1]
    __shared__ float h1s[BPW][HD];        // layer1 hidden h1[tau-2]
    __shared__ float g0s[BPW][4 * HD];    // layer0 gate pre-acts (no bias)
    __shared__ float p1s[BPW][4 * HD];    // Wih1 @ h0 partial
    __shared__ float p2s[BPW][4 * HD];    // Whh1 @ h1 partial
    __shared__ float xs[BPW][64];         // x tile (64 timesteps)
    __shared__ float b0s[4 * HD];         // folded biases layer0
    __shared__ float b1s[4 * HD];         // folded biases layer1
    __shared__ float hids[BPW][HD / 2];   // classifier hidden

    const int tid = threadIdx.x;
    const int m   = tid >> 8;             // 0: Whh0, 1: Wih1, 2: Whh1 (wave-uniform)
    const int r   = tid & 255;            // gate row
    const int b0  = blockIdx.x * BPW;

    // each thread owns one 64-float weight row in registers (64 VGPRs)
    const float* wrow = (m == 0 ? Whh0 : (m == 1 ? Wih1 : Whh1)) + r * HD;
    float4 wv[16];
#pragma unroll
    for (int i = 0; i < 16; ++i) wv[i] = reinterpret_cast<const float4*>(wrow)[i];
    const float wx = (m == 0) ? Wih0[r] : 0.0f;   // D==1 input weight column

    if (tid < 256)      b0s[tid]       = bih0[tid] + bhh0[tid];
    else if (tid < 512) b1s[tid - 256] = bih1[tid - 256] + bhh1[tid - 256];

    if (tid < BPW * HD) {
        (&h0s[0][0])[tid] = 0.0f;
        (&h1s[0][0])[tid] = 0.0f;
    }
    float c0 = 0.0f;  // cell state, layer0: held by threads 0..511   (b=tid>>6, j=tid&63)
    float c1 = 0.0f;  // cell state, layer1: threads 512..767 -> b 0..3; threads 0..255 -> b 4..7

    __syncthreads();

    // iteration tau: layer0 computes step tau (needs h0[tau-1]),
    //                layer1 computes step tau-1 (needs h0[tau-1], h1[tau-2]).
    for (int t = 0; t <= T; ++t) {
        if ((t & 63) == 0 && t < T) {
            if (tid < BPW * 64) {
                int bb = tid >> 6, tt = tid & 63;
                if (t + tt < T)
                    xs[bb][tt] = x[(size_t)(b0 + bb) * T + t + tt];
            }
            __syncthreads();
        }

        // ---- P1: three 256x64 matvecs, all waves busy --------------------
        if (m == 0) {
            if (t < T) {
                float acc[BPW];
#pragma unroll
                for (int b = 0; b < BPW; ++b) acc[b] = xs[b][t & 63] * wx;
#pragma unroll
                for (int kc = 0; kc < 16; ++kc) {
                    float4 w = wv[kc];
#pragma unroll
                    for (int b = 0; b < BPW; ++b) {
                        float4 h = *reinterpret_cast<const float4*>(&h0s[b][kc * 4]);
                        acc[b] += w.x * h.x;
                        acc[b] += w.y * h.y;
                        acc[b] += w.z * h.z;
                        acc[b] += w.w * h.w;
                    }
                }
#pragma unroll
                for (int b = 0; b < BPW; ++b) g0s[b][r] = acc[b];
            }
        } else if (m == 1) {
            if (t >= 1) {
                float acc[BPW];
#pragma unroll
                for (int b = 0; b < BPW; ++b) acc[b] = 0.0f;
#pragma unroll
                for (int kc = 0; kc < 16; ++kc) {
                    float4 w = wv[kc];
#pragma unroll
                    for (int b = 0; b < BPW; ++b) {
                        float4 h = *reinterpret_cast<const float4*>(&h0s[b][kc * 4]);
                        acc[b] += w.x * h.x;
                        acc[b] += w.y * h.y;
                        acc[b] += w.z * h.z;
                        acc[b] += w.w * h.w;
                    }
                }
#pragma unroll
                for (int b = 0; b < BPW; ++b) p1s[b][r] = acc[b];
            }
        } else {
            if (t >= 1) {
                float acc[BPW];
#pragma unroll
                for (int b = 0; b < BPW; ++b) acc[b] = 0.0f;
#pragma unroll
                for (int kc = 0; kc < 16; ++kc) {
                    float4 w = wv[kc];
#pragma unroll
                    for (int b = 0; b < BPW; ++b) {
                        float4 h = *reinterpret_cast<const float4*>(&h1s[b][kc * 4]);
                        acc[b] += w.x * h.x;
                        acc[b] += w.y * h.y;
                        acc[b] += w.z * h.z;
                        acc[b] += w.w * h.w;
                    }
                }
#pragma unroll
                for (int b = 0; b < BPW; ++b) p2s[b][r] = acc[b];
            }
        }
        __syncthreads();

        // ---- P2: nonlinearities + state update ---------------------------
        if (t < T && tid < BPW * HD) {               // layer0 update, step t
            const int bb = tid >> 6, j = tid & 63;
            float pi = g0s[bb][j]          + b0s[j];
            float pf = g0s[bb][HD + j]     + b0s[HD + j];
            float pg = g0s[bb][2 * HD + j] + b0s[2 * HD + j];
            float po = g0s[bb][3 * HD + j] + b0s[3 * HD + j];
            float iv = fast_sig(pi), fv = fast_sig(pf);
            float gv = fast_tanh(pg), ov = fast_sig(po);
            c0 = fv * c0 + iv * gv;
            h0s[bb][j] = ov * fast_tanh(c0);
        }
        if (t >= 1) {                                // layer1 update, step t-1
            if (tid >= 512) {
                const int bb = (tid - 512) >> 6, j = tid & 63;
                float pi = p1s[bb][j]          + p2s[bb][j]          + b1s[j];
                float pf = p1s[bb][HD + j]     + p2s[bb][HD + j]     + b1s[HD + j];
                float pg = p1s[bb][2 * HD + j] + p2s[bb][2 * HD + j] + b1s[2 * HD + j];
                float po = p1s[bb][3 * HD + j] + p2s[bb][3 * HD + j] + b1s[3 * HD + j];
                float iv = fast_sig(pi), fv = fast_sig(pf);
                float gv = fast_tanh(pg), ov = fast_sig(po);
                c1 = fv * c1 + iv * gv;
                h1s[bb][j] = ov * fast_tanh(c1);
            } else if (tid < 256) {
                const int bb = 4 + (tid >> 6), j = tid & 63;
                float pi = p1s[bb][j]          + p2s[bb][j]          + b1s[j];
                float pf = p1s[bb][HD + j]     + p2s[bb][HD + j]     + b1s[HD + j];
                float pg = p1s[bb][2 * HD + j] + p2s[bb][2 * HD + j] + b1s[2 * HD + j];
                float po = p1s[bb][3 * HD + j] + p2s[bb][3 * HD + j] + b1s[3 * HD + j];
                float iv = fast_sig(pi), fv = fast_sig(pf);
                float gv = fast_tanh(pg), ov = fast_sig(po);
                c1 = fv * c1 + iv * gv;
                h1s[bb][j] = ov * fast_tanh(c1);
            }
        }
        __syncthreads();
    }

    // ---- classifier head: relu(h_n @ Wc1^T + bc1) @ Wc2^T + bc2 ----------
    if (tid < 256) {
        const int bb = tid >> 5, jh = tid & 31;
        float acc = bc1[jh];
        const float* wr = Wc1 + jh * HD;
#pragma unroll
        for (int k = 0; k < HD; ++k) acc += wr[k] * h1s[bb][k];
        hids[bb][jh] = fmaxf(acc, 0.0f);
    }
    __syncthreads();
    if (tid < BPW) {
        float acc = bc2[0];
#pragma unroll
        for (int k = 0; k < HD / 2; ++k) acc += Wc2[k] * hids[tid][k];
        out[b0 + tid] = acc;
    }
}

extern "C" void kernel_launch(void* const* d_in, const int* in_sizes, int n_in,
                              void* d_out, int out_size, void* d_ws, size_t ws_size,
                              hipStream_t stream) {
    const float* x    = (const float*)d_in[0];
    const float* Wih0 = (const float*)d_in[1];
    const float* Whh0 = (const float*)d_in[2];
    const float* bih0 = (const float*)d_in[3];
    const float* bhh0 = (const float*)d_in[4];
    const float* Wih1 = (const float*)d_in[5];
    const float* Whh1 = (const float*)d_in[6];
    const float* bih1 = (const float*)d_in[7];
    const float* bhh1 = (const float*)d_in[8];
    const float* Wc1  = (const float*)d_in[9];
    const float* bc1  = (const float*)d_in[10];
    const float* Wc2  = (const float*)d_in[11];
    const float* bc2  = (const float*)d_in[12];

    const int B = out_size;            // output is [B,1]
    const int T = in_sizes[0] / B;     // x is [B,T,1]

    dim3 grid(B / BPW), block(NT);
    hipLaunchKernelGGL(lstm2_kernel, grid, block, 0, stream,
                       x, Wih0, Whh0, bih0, bhh0,
                       Wih1, Whh1, bih1, bhh1,
                       Wc1, bc1, Wc2, bc2, (float*)d_out, B, T);
}

// Round 2
// 1477.355 us; speedup vs baseline: 3.2474x; 3.2474x over previous
//
#include <hip/hip_runtime.h>

typedef _Float16 f16;
typedef _Float16 f16x8 __attribute__((ext_vector_type(8)));
typedef float    f32x4 __attribute__((ext_vector_type(4)));

#define HD  64
#define BPW 8        // real batches per block (cols 8..15 of N-tile are padding)
#define NT  768      // 12 waves
#define SCL 2048.0f
#define ISC (1.0f / 2048.0f)

__device__ __forceinline__ float fast_sig(float x) {
    return __builtin_amdgcn_rcpf(1.0f + __expf(-x));
}
__device__ __forceinline__ float fast_tanh(float x) {
    float e = __expf(2.0f * x);
    return (e - 1.0f) * __builtin_amdgcn_rcpf(e + 1.0f);
}
__device__ __forceinline__ f32x4 MFMA(f16x8 a, f16x8 b, f32x4 c) {
    return __builtin_amdgcn_mfma_f32_16x16x32_f16(a, b, c, 0, 0, 0);
}

// Layout notes (verified layouts from guide):
//  A-frag 16x16x32: A[m = lane&15][k = (lane>>4)*8 + j], j=0..7
//  B-frag:          B[k = (lane>>4)*8 + j][n = lane&15]
//  C/D:             col = lane&15, row = (lane>>4)*4 + reg
// Gate-interleaved row permutation: permuted row R = 4*j_hidden + gate, so a
// C-tile lane (q,n) holds gates i,f,g,o of hidden unit j = tile*4+q in regs 0..3.

extern "C" __global__ void __launch_bounds__(NT, 3)
lstm2_mfma(const float* __restrict__ x,
           const float* __restrict__ Wih0, const float* __restrict__ Whh0,
           const float* __restrict__ bih0, const float* __restrict__ bhh0,
           const float* __restrict__ Wih1, const float* __restrict__ Whh1,
           const float* __restrict__ bih1, const float* __restrict__ bhh1,
           const float* __restrict__ Wc1,  const float* __restrict__ bc1,
           const float* __restrict__ Wc2,  const float* __restrict__ bc2,
           float* __restrict__ out, int B, int T)
{
    // B-frag buffer in lane-major order: bBuf[prec][kf][lane][j]
    // k_global = kf*32 + (lane>>4)*8 + j ; k 0..63 = h0, 64..127 = h1
    __shared__ __align__(16) f16 bBuf[2][4][64][8];
    __shared__ float xs[BPW][64];
    __shared__ float hf[16][HD];
    __shared__ __align__(16) float b0p[256];
    __shared__ __align__(16) float wxp[256];
    __shared__ __align__(16) float b1p[256];
    __shared__ float hid[BPW][HD / 2];

    const int tid  = threadIdx.x;
    const int wave = tid >> 6;
    const int lane = tid & 63;
    const int q    = lane >> 4;
    const int n    = lane & 15;
    const int b0   = blockIdx.x * BPW;
    const bool isL0 = (wave < 4);

    { // zero the h frag buffer (h0[-1] = h1[-1] = 0)
        int* p = (int*)&bBuf[0][0][0][0];
        for (int i = tid; i < 2048; i += NT) p[i] = 0;
    }
    if (tid < 256) {  // permuted folded biases + Wih0 column (D==1)
        int g = tid & 3, jh = tid >> 2;
        b0p[tid] = bih0[g * HD + jh] + bhh0[g * HD + jh];
        wxp[tid] = Wih0[g * HD + jh];
        b1p[tid] = bih1[g * HD + jh] + bhh1[g * HD + jh];
    }

    // ---- persistent A-frags (weights), f16 hi + scaled-lo split ----------
    f16x8 Ahi[8], Alo[8];
    if (isL0) {
#pragma unroll
        for (int u = 0; u < 4; ++u) {
            int R = (wave * 4 + u) * 16 + n;       // n plays role of m here
            int g = R & 3, jh = R >> 2;
            const float* src = Whh0 + (size_t)(g * HD + jh) * HD;
#pragma unroll
            for (int kf = 0; kf < 2; ++kf) {
                const float* s8 = src + kf * 32 + q * 8;
                f16x8 hi, lo;
#pragma unroll
                for (int j = 0; j < 8; ++j) {
                    float v = s8[j];
                    f16 h = (f16)v;
                    hi[j] = h;
                    lo[j] = (f16)((v - (float)h) * SCL);
                }
                Ahi[u * 2 + kf] = hi; Alo[u * 2 + kf] = lo;
            }
        }
    } else {
#pragma unroll
        for (int u = 0; u < 2; ++u) {
            int R = ((wave - 4) * 2 + u) * 16 + n;
            int g = R & 3, jh = R >> 2;
#pragma unroll
            for (int kf = 0; kf < 4; ++kf) {
                const float* s8 = (kf < 2
                    ? Wih1 + (size_t)(g * HD + jh) * HD + kf * 32
                    : Whh1 + (size_t)(g * HD + jh) * HD + (kf - 2) * 32) + q * 8;
                f16x8 hi, lo;
#pragma unroll
                for (int j = 0; j < 8; ++j) {
                    float v = s8[j];
                    f16 h = (f16)v;
                    hi[j] = h;
                    lo[j] = (f16)((v - (float)h) * SCL);
                }
                Ahi[u * 4 + kf] = hi; Alo[u * 4 + kf] = lo;
            }
        }
    }

    float c[4]  = {0.f, 0.f, 0.f, 0.f};
    float hq[4] = {0.f, 0.f, 0.f, 0.f};
    __syncthreads();

    // iteration t: layer0 computes step t, layer1 computes step t-1
#pragma unroll 1
    for (int t = 0; t <= T; ++t) {
        if ((t & 63) == 0 && t < T) {
            if (tid < BPW * 64) {
                int nn = tid >> 6, tt2 = tid & 63;
                xs[nn][tt2] = (t + tt2 < T) ? x[(size_t)(b0 + nn) * T + t + tt2]
                                            : 0.0f;
            }
            __syncthreads();
        }

        // ---- Phase A: MFMA gates + in-register LSTM cell update ----------
        if (isL0) {
            if (t < T) {
                f16x8 bh0 = *(const f16x8*)&bBuf[0][0][lane][0];
                f16x8 bh1 = *(const f16x8*)&bBuf[0][1][lane][0];
                f16x8 bl0 = *(const f16x8*)&bBuf[1][0][lane][0];
                f16x8 bl1 = *(const f16x8*)&bBuf[1][1][lane][0];
                float xv = (n < BPW) ? xs[n][t & 63] : 0.0f;
#pragma unroll
                for (int u = 0; u < 4; ++u) {
                    int tt = wave * 4 + u;
                    f32x4 bb = *(const f32x4*)&b0p[tt * 16 + q * 4];
                    f32x4 wx = *(const f32x4*)&wxp[tt * 16 + q * 4];
                    f32x4 acc;
                    acc[0] = bb[0] + wx[0] * xv;
                    acc[1] = bb[1] + wx[1] * xv;
                    acc[2] = bb[2] + wx[2] * xv;
                    acc[3] = bb[3] + wx[3] * xv;
                    acc = MFMA(Ahi[u * 2 + 0], bh0, acc);
                    acc = MFMA(Ahi[u * 2 + 1], bh1, acc);
                    f32x4 a2 = {0.f, 0.f, 0.f, 0.f};
                    a2 = MFMA(Ahi[u * 2 + 0], bl0, a2);
                    a2 = MFMA(Ahi[u * 2 + 1], bl1, a2);
                    a2 = MFMA(Alo[u * 2 + 0], bh0, a2);
                    a2 = MFMA(Alo[u * 2 + 1], bh1, a2);
                    float gi = acc[0] + a2[0] * ISC;
                    float gf = acc[1] + a2[1] * ISC;
                    float gg = acc[2] + a2[2] * ISC;
                    float go = acc[3] + a2[3] * ISC;
                    float iv = fast_sig(gi), fv = fast_sig(gf);
                    float gv = fast_tanh(gg), ov = fast_sig(go);
                    c[u] = fv * c[u] + iv * gv;
                    hq[u] = ov * fast_tanh(c[u]);
                }
            }
        } else {
            if (t >= 1) {
                f16x8 bh[4], bl[4];
#pragma unroll
                for (int kf = 0; kf < 4; ++kf) {
                    bh[kf] = *(const f16x8*)&bBuf[0][kf][lane][0];
                    bl[kf] = *(const f16x8*)&bBuf[1][kf][lane][0];
                }
#pragma unroll
                for (int u = 0; u < 2; ++u) {
                    int tt = (wave - 4) * 2 + u;
                    f32x4 acc = *(const f32x4*)&b1p[tt * 16 + q * 4];
                    f32x4 a2  = {0.f, 0.f, 0.f, 0.f};
#pragma unroll
                    for (int kf = 0; kf < 4; ++kf) {
                        acc = MFMA(Ahi[u * 4 + kf], bh[kf], acc);
                        a2  = MFMA(Ahi[u * 4 + kf], bl[kf], a2);
                        a2  = MFMA(Alo[u * 4 + kf], bh[kf], a2);
                    }
                    float gi = acc[0] + a2[0] * ISC;
                    float gf = acc[1] + a2[1] * ISC;
                    float gg = acc[2] + a2[2] * ISC;
                    float go = acc[3] + a2[3] * ISC;
                    float iv = fast_sig(gi), fv = fast_sig(gf);
                    float gv = fast_tanh(gg), ov = fast_sig(go);
                    c[u] = fv * c[u] + iv * gv;
                    hq[u] = ov * fast_tanh(c[u]);
                }
            }
        }
        __syncthreads();

        // ---- Phase B: publish h as f16 hi/lo into B-frag buffer ----------
        if (isL0) {
            if (t < T) {
#pragma unroll
                for (int u = 0; u < 4; ++u) {
                    int jh = (wave * 4 + u) * 4 + q;          // k = jh (0..63)
                    int kf = jh >> 5, qk = (jh >> 3) & 3, j = jh & 7;
                    float h = hq[u];
                    f16 hh = (f16)h;
                    bBuf[0][kf][qk * 16 + n][j] = hh;
                    bBuf[1][kf][qk * 16 + n][j] = (f16)((h - (float)hh) * SCL);
                }
            }
        } else {
            if (t >= 1) {
#pragma unroll
                for (int u = 0; u < 2; ++u) {
                    int jh = ((wave - 4) * 2 + u) * 4 + q;    // k = 64 + jh
                    int kf = 2 + (jh >> 5), qk = (jh >> 3) & 3, j = jh & 7;
                    float h = hq[u];
                    f16 hh = (f16)h;
                    bBuf[0][kf][qk * 16 + n][j] = hh;
                    bBuf[1][kf][qk * 16 + n][j] = (f16)((h - (float)hh) * SCL);
                    if (t == T) hf[n][jh] = h;                // final h1, fp32
                }
            }
        }
        __syncthreads();
    }

    // ---- classifier: relu(h1 @ Wc1^T + bc1) @ Wc2^T + bc2 ---------------
    if (tid < BPW * 32) {
        int nn = tid >> 5, m = tid & 31;
        float acc = bc1[m];
        const float* wr = Wc1 + m * HD;
#pragma unroll
        for (int k = 0; k < HD; ++k) acc += wr[k] * hf[nn][k];
        hid[nn][m] = fmaxf(acc, 0.0f);
    }
    __syncthreads();
    if (tid < BPW) {
        float acc = bc2[0];
#pragma unroll
        for (int k = 0; k < HD / 2; ++k) acc += Wc2[k] * hid[tid][k];
        out[b0 + tid] = acc;
    }
}

extern "C" void kernel_launch(void* const* d_in, const int* in_sizes, int n_in,
                              void* d_out, int out_size, void* d_ws, size_t ws_size,
                              hipStream_t stream) {
    const float* x    = (const float*)d_in[0];
    const float* Wih0 = (const float*)d_in[1];
    const float* Whh0 = (const float*)d_in[2];
    const float* bih0 = (const float*)d_in[3];
    const float* bhh0 = (const float*)d_in[4];
    const float* Wih1 = (const float*)d_in[5];
    const float* Whh1 = (const float*)d_in[6];
    const float* bih1 = (const float*)d_in[7];
    const float* bhh1 = (const float*)d_in[8];
    const float* Wc1  = (const float*)d_in[9];
    const float* bc1  = (const float*)d_in[10];
    const float* Wc2  = (const float*)d_in[11];
    const float* bc2  = (const float*)d_in[12];

    const int B = out_size;            // output [B,1]
    const int T = in_sizes[0] / B;     // x is [B,T,1]

    dim3 grid(B / BPW), block(NT);
    hipLaunchKernelGGL(lstm2_mfma, grid, block, 0, stream,
                       x, Wih0, Whh0, bih0, bhh0,
                       Wih1, Whh1, bih1, bhh1,
                       Wc1, bc1, Wc2, bc2, (float*)d_out, B, T);
}

// Round 3
// 1380.064 us; speedup vs baseline: 3.4763x; 1.0705x over previous
//
#include <hip/hip_runtime.h>

typedef _Float16 f16;
typedef _Float16 f16x8 __attribute__((ext_vector_type(8)));
typedef float    f32x4 __attribute__((ext_vector_type(4)));

#define HD   64
#define BPW  8        // real batches per block (N-cols 8..15 padding)
#define NT   512      // 8 waves: 4 layer-0 + 4 layer-1
#define TMAX 1024
#define SCL  2048.0f
#define ISC  (1.0f / 2048.0f)

__device__ __forceinline__ float fast_sig(float x) {
    return __builtin_amdgcn_rcpf(1.0f + __expf(-x));
}
__device__ __forceinline__ float fast_tanh(float x) {
    float e = __expf(2.0f * x);
    return (e - 1.0f) * __builtin_amdgcn_rcpf(e + 1.0f);
}
__device__ __forceinline__ f32x4 MFMA(f16x8 a, f16x8 b, f32x4 c) {
    return __builtin_amdgcn_mfma_f32_16x16x32_f16(a, b, c, 0, 0, 0);
}

// unit->k permutation: unit jh (tile=jh>>2, q=jh&3) stored at
//   k = (tile>>3)*32 + ((tile>>1)&3)*8 + q*2 + (tile&1)
// chosen so Phase-B ds_write_b16 banks = (4n+q)%32 -> 2-way max (free).
__device__ __forceinline__ int kinv(int k) {   // k -> unit
    int kf = k >> 5, qk = (k >> 3) & 3, j = k & 7;
    int tile = (kf << 3) | (qk << 1) | (j & 1);
    return tile * 4 + (j >> 1);
}

extern "C" __global__ void __launch_bounds__(NT, 2)
lstm2_mfma3(const float* __restrict__ x,
            const float* __restrict__ Wih0, const float* __restrict__ Whh0,
            const float* __restrict__ bih0, const float* __restrict__ bhh0,
            const float* __restrict__ Wih1, const float* __restrict__ Whh1,
            const float* __restrict__ bih1, const float* __restrict__ bhh1,
            const float* __restrict__ Wc1,  const float* __restrict__ bc1,
            const float* __restrict__ Wc2,  const float* __restrict__ bc2,
            float* __restrict__ out, int B, int T)
{
    // [buf][prec][kf][row=q*16+n][j]; k(frag-local) = q*8+j; kf 0..1 h0, 2..3 h1
    __shared__ __align__(16) f16 bBuf[2][2][4][64][8];   // 16 KB
    __shared__ float xs[TMAX][BPW];                      // 32 KB
    __shared__ float hf[16][HD];
    __shared__ float hid[BPW][HD / 2];

    const int tid  = threadIdx.x;
    const int wave = tid >> 6;
    const int lane = tid & 63;
    const int q    = lane >> 4;
    const int n    = lane & 15;
    const int b0   = blockIdx.x * BPW;
    const bool isL0 = (wave < 4);

    { // zero both h frag buffers (h0(-1)=h1(-1)=0 and the stale halves)
        int* p = (int*)&bBuf[0][0][0][0][0];
        for (int i = tid; i < 4096; i += NT) p[i] = 0;
    }
    // preload entire x slice for this block's batches
    for (int idx = tid; idx < (BPW * T) / 4; idx += NT) {
        int fl = idx * 4;
        int bb = fl / T, tt = fl - bb * T;
        float4 v = *reinterpret_cast<const float4*>(&x[(size_t)(b0 + bb) * T + tt]);
        xs[tt + 0][bb] = v.x; xs[tt + 1][bb] = v.y;
        xs[tt + 2][bb] = v.z; xs[tt + 3][bb] = v.w;
    }

    // ---- persistent A-frags + register-resident biases --------------------
    f16x8 Ahi[16], Alo[16];
    f32x4 bias[4];
    f32x4 wxv[4];
    const int mrow = n;                 // A row within tile
    const int gA   = mrow & 3;          // gate of A row (gate-interleaved)
    if (isL0) {
#pragma unroll
        for (int u = 0; u < 4; ++u) {
            const int tt = wave * 4 + u;
            const int rowA = gA * HD + (tt * 4 + (mrow >> 2));
#pragma unroll
            for (int kf = 0; kf < 2; ++kf) {
                f16x8 hi, lo;
#pragma unroll
                for (int j = 0; j < 8; ++j) {
                    float v = Whh0[(size_t)rowA * HD + kinv(kf * 32 + q * 8 + j)];
                    f16 h = (f16)v;
                    hi[j] = h; lo[j] = (f16)((v - (float)h) * SCL);
                }
                Ahi[u * 2 + kf] = hi; Alo[u * 2 + kf] = lo;
            }
            const int uc = tt * 4 + q;  // C-row unit for this lane
#pragma unroll
            for (int g = 0; g < 4; ++g) {
                bias[u][g] = bih0[g * HD + uc] + bhh0[g * HD + uc];
                wxv[u][g]  = Wih0[g * HD + uc];
            }
        }
    } else {
#pragma unroll
        for (int u = 0; u < 4; ++u) {
            const int tt = (wave - 4) * 4 + u;
            const int rowA = gA * HD + (tt * 4 + (mrow >> 2));
#pragma unroll
            for (int kf = 0; kf < 4; ++kf) {
                f16x8 hi, lo;
#pragma unroll
                for (int j = 0; j < 8; ++j) {
                    int kg = kf * 32 + q * 8 + j;
                    float v = (kg < 64)
                        ? Wih1[(size_t)rowA * HD + kinv(kg)]
                        : Whh1[(size_t)rowA * HD + kinv(kg - 64)];
                    f16 h = (f16)v;
                    hi[j] = h; lo[j] = (f16)((v - (float)h) * SCL);
                }
                Ahi[u * 4 + kf] = hi; Alo[u * 4 + kf] = lo;
            }
            const int uc = tt * 4 + q;
#pragma unroll
            for (int g = 0; g < 4; ++g)
                bias[u][g] = bih1[g * HD + uc] + bhh1[g * HD + uc];
        }
    }

    float c[4] = {0.f, 0.f, 0.f, 0.f};
    __syncthreads();

    // iteration t: layer0 step t (reads h0(t-1)), layer1 step t-1
    // (reads h0(t-1), h1(t-2)); both live in bBuf[t&1]; writes go to bBuf[~t&1].
#pragma unroll 1
    for (int t = 0; t <= T; ++t) {
        const int par = t & 1;
        if (isL0) {
            if (t < T) {
                f16x8 bh0 = *(const f16x8*)&bBuf[par][0][0][lane][0];
                f16x8 bh1 = *(const f16x8*)&bBuf[par][0][1][lane][0];
                f16x8 bl0 = *(const f16x8*)&bBuf[par][1][0][lane][0];
                f16x8 bl1 = *(const f16x8*)&bBuf[par][1][1][lane][0];
                float xv = (n < BPW) ? xs[t][n] : 0.0f;
                float hq[4];
#pragma unroll
                for (int u = 0; u < 4; ++u) {
                    f32x4 acc;
#pragma unroll
                    for (int g = 0; g < 4; ++g) acc[g] = bias[u][g] + wxv[u][g] * xv;
                    acc = MFMA(Ahi[u * 2 + 0], bh0, acc);
                    acc = MFMA(Ahi[u * 2 + 1], bh1, acc);
                    f32x4 a2 = {0.f, 0.f, 0.f, 0.f};
                    a2 = MFMA(Ahi[u * 2 + 0], bl0, a2);
                    a2 = MFMA(Ahi[u * 2 + 1], bl1, a2);
                    a2 = MFMA(Alo[u * 2 + 0], bh0, a2);
                    a2 = MFMA(Alo[u * 2 + 1], bh1, a2);
                    float gi = acc[0] + a2[0] * ISC;
                    float gf = acc[1] + a2[1] * ISC;
                    float gg = acc[2] + a2[2] * ISC;
                    float go = acc[3] + a2[3] * ISC;
                    float iv = fast_sig(gi), fv = fast_sig(gf);
                    float gv = fast_tanh(gg), ov = fast_sig(go);
                    c[u] = fv * c[u] + iv * gv;
                    hq[u] = ov * fast_tanh(c[u]);
                }
#pragma unroll
                for (int u = 0; u < 4; ++u) {   // publish h0(t) -> buf par^1
                    const int tt = wave * 4 + u;
                    const int kf = tt >> 3, qk = (tt >> 1) & 3;
                    const int jb = (q << 1) | (tt & 1);
                    float h = hq[u];
                    f16 hh = (f16)h;
                    bBuf[par ^ 1][0][kf][qk * 16 + n][jb] = hh;
                    bBuf[par ^ 1][1][kf][qk * 16 + n][jb] = (f16)((h - (float)hh) * SCL);
                }
            }
        } else {
            if (t >= 1) {
                f16x8 bh[4], bl[4];
#pragma unroll
                for (int kf = 0; kf < 4; ++kf) {
                    bh[kf] = *(const f16x8*)&bBuf[par][0][kf][lane][0];
                    bl[kf] = *(const f16x8*)&bBuf[par][1][kf][lane][0];
                }
                float hq[4];
#pragma unroll
                for (int u = 0; u < 4; ++u) {
                    f32x4 acc = bias[u];
                    f32x4 a2  = {0.f, 0.f, 0.f, 0.f};
#pragma unroll
                    for (int kf = 0; kf < 4; ++kf) {
                        acc = MFMA(Ahi[u * 4 + kf], bh[kf], acc);
                        a2  = MFMA(Ahi[u * 4 + kf], bl[kf], a2);
                        a2  = MFMA(Alo[u * 4 + kf], bh[kf], a2);
                    }
                    float gi = acc[0] + a2[0] * ISC;
                    float gf = acc[1] + a2[1] * ISC;
                    float gg = acc[2] + a2[2] * ISC;
                    float go = acc[3] + a2[3] * ISC;
                    float iv = fast_sig(gi), fv = fast_sig(gf);
                    float gv = fast_tanh(gg), ov = fast_sig(go);
                    c[u] = fv * c[u] + iv * gv;
                    hq[u] = ov * fast_tanh(c[u]);
                }
#pragma unroll
                for (int u = 0; u < 4; ++u) {   // publish h1(t-1) -> buf par^1
                    const int tt = (wave - 4) * 4 + u;
                    const int kf = 2 + (tt >> 3), qk = (tt >> 1) & 3;
                    const int jb = (q << 1) | (tt & 1);
                    float h = hq[u];
                    f16 hh = (f16)h;
                    bBuf[par ^ 1][0][kf][qk * 16 + n][jb] = hh;
                    bBuf[par ^ 1][1][kf][qk * 16 + n][jb] = (f16)((h - (float)hh) * SCL);
                    if (t == T) hf[n][tt * 4 + q] = h;  // final h1, fp32
                }
            }
        }
        __syncthreads();
    }

    // ---- classifier: relu(h1 @ Wc1^T + bc1) @ Wc2^T + bc2 ----------------
    if (tid < BPW * 32) {
        int nn = tid >> 5, m = tid & 31;
        float acc = bc1[m];
        const float* wr = Wc1 + m * HD;
#pragma unroll
        for (int k = 0; k < HD; ++k) acc += wr[k] * hf[nn][k];
        hid[nn][m] = fmaxf(acc, 0.0f);
    }
    __syncthreads();
    if (tid < BPW) {
        float acc = bc2[0];
#pragma unroll
        for (int k = 0; k < HD / 2; ++k) acc += Wc2[k] * hid[tid][k];
        out[b0 + tid] = acc;
    }
}

extern "C" void kernel_launch(void* const* d_in, const int* in_sizes, int n_in,
                              void* d_out, int out_size, void* d_ws, size_t ws_size,
                              hipStream_t stream) {
    const float* x    = (const float*)d_in[0];
    const float* Wih0 = (const float*)d_in[1];
    const float* Whh0 = (const float*)d_in[2];
    const float* bih0 = (const float*)d_in[3];
    const float* bhh0 = (const float*)d_in[4];
    const float* Wih1 = (const float*)d_in[5];
    const float* Whh1 = (const float*)d_in[6];
    const float* bih1 = (const float*)d_in[7];
    const float* bhh1 = (const float*)d_in[8];
    const float* Wc1  = (const float*)d_in[9];
    const float* bc1  = (const float*)d_in[10];
    const float* Wc2  = (const float*)d_in[11];
    const float* bc2  = (const float*)d_in[12];

    const int B = out_size;            // output [B,1]
    const int T = in_sizes[0] / B;     // x is [B,T,1]

    dim3 grid(B / BPW), block(NT);
    hipLaunchKernelGGL(lstm2_mfma3, grid, block, 0, stream,
                       x, Wih0, Whh0, bih0, bhh0,
                       Wih1, Whh1, bih1, bhh1,
                       Wc1, bc1, Wc2, bc2, (float*)d_out, B, T);
}